// Round 2
// 67.928 us; speedup vs baseline: 1.0127x; 1.0127x over previous
//
#include <hip/hip_runtime.h>

#define BIGF 1e30f

constexpr int T   = 128;    // trajectory points
constexpr int NB  = 16;     // roads
constexpr int NP  = 256;    // points per road
constexpr int NS  = NP - 1; // segments per branch (255)
constexpr int NB2 = 2 * NB; // fw + bw branches (32)

struct alignas(16) Smem {
  float P[NP * 3];                // branch points, FORWARD order, flat xyz (float4-aligned)
  float q[T * 3];                 // trajectory, flat xyz (float4-aligned)
  float sl[2][NS];                // segment lengths per dir (0=fw, 1=bw)
  float t0[2][NS];                // p0 projection parameter per dir
  float cum[2][NP];               // cumulative arc length per dir, cum[d][0]=0
  float tcum[T];                  // trajectory cumulative length
  unsigned char pmask[NP];        // point mask (forward order)
  unsigned long long wmask[4];    // fw-segment-valid ballot per wave
  float wsumA[4], wsumB[4], wsumC[4]; // scan wave totals (sl_fw, sl_bw, traj)
  float argf[2][4]; int argi[2][4];   // p0-argmin per-wave results, per dir
  float distf[4];                 // distance-sum per-wave results (separate: no WAR)
};

// ---- mask dtype sniffing (uniform scalar loads, broadcast — effectively free):
// lengths >= 2 guarantees mask[0,0,0]=mask[0,0,1]=true ----
__device__ __forceinline__ int sniff_mask_kind(const void* rm) {
  const unsigned char* u = (const unsigned char*)rm;
  unsigned char b0 = u[0], b1 = u[1], b4 = u[4];
  if (b0 == 1 && b1 == 1) return 0;                  // u8 / bool
  if (b0 == 1 && b1 == 0) return (b4 == 1) ? 1 : 2;  // i32 : i64
  if (b0 == 0) return 4;                             // f32
  return 3;                                          // bf16
}

__device__ __forceinline__ bool read_mask(const void* rm, int kind, int idx) {
  switch (kind) {
    case 0:  return ((const unsigned char*)rm)[idx] != 0;
    case 1:  return ((const int*)rm)[idx] != 0;
    case 2:  return ((const long long*)rm)[idx] != 0;
    case 3:  { unsigned short v = ((const unsigned short*)rm)[idx];
               return (unsigned short)(v << 1) != 0; }
    default: return ((const float*)rm)[idx] != 0.0f;
  }
}

// k1: one block per (n, road). Handles BOTH fw (waves 0-1) and bw (waves 2-3)
// directions from a single forward-order staging. bw segment i uses points
// (NP-1-i, NP-2-i) — arithmetic identical to the old reversed-staging blocks.
// NOTE (R5 lesson): do NOT fuse selection via per-block __threadfence/semaphore —
// device-scope release fences cost ~55 µs; the stream-ordered kernel boundary
// to k2 is the free release/acquire.
__global__ __launch_bounds__(256) void k1_costs(const float* __restrict__ traj,
                                                const float* __restrict__ rp,
                                                const void* __restrict__ rm,
                                                float* cost_ws, float* proj_ws) {
  __shared__ Smem s;
  const int tid  = threadIdx.x;
  const int lane = tid & 63;
  const int w    = tid >> 6;
  const int n    = (int)blockIdx.x >> 4;       // blockIdx = n*NB + r
  const int r    = (int)blockIdx.x & (NB - 1);
  const int mkind = sniff_mask_kind(rm);

  // --- stage: fully coalesced float4 loads, forward order only ---
  if (tid < 192) {  // NP*3/4 = 192 float4s per branch
    float4 v = ((const float4*)rp)[(size_t)(n * NB + r) * 192 + tid];
    ((float4*)s.P)[tid] = v;
  }
  if (tid < 96) {   // T*3/4 = 96 float4s per sample
    float4 v = ((const float4*)traj)[(size_t)n * 96 + tid];
    ((float4*)s.q)[tid] = v;
  }
  s.pmask[tid] = read_mask(rm, mkind, (n * NB + r) * NP + tid) ? 1 : 0;
  __syncthreads();                              // B1: staging complete

  // --- per-segment data + p0 projection candidate, BOTH dirs per thread ---
  float d2f = BIGF, d2b = BIGF;
  int   idxf = tid, idxb = tid;
  float slf = 0.0f, slb = 0.0f;
  int   smf = 0;
  if (tid < NS) {
    const float p0x = s.q[0], p0y = s.q[1], p0z = s.q[2];
    {   // forward segment tid: points (tid, tid+1)
      float ax = s.P[3*tid],   ay = s.P[3*tid+1], az = s.P[3*tid+2];
      float svx = s.P[3*tid+3] - ax, svy = s.P[3*tid+4] - ay, svz = s.P[3*tid+5] - az;
      smf = s.pmask[tid] & s.pmask[tid + 1];
      float svd2 = svx*svx + svy*svy + svz*svz;
      slf = smf ? sqrtf(svd2) : 0.0f;
      s.sl[0][tid] = slf;
      float dx = p0x - ax, dy = p0y - ay, dz = p0z - az;
      float t0v = fminf(fmaxf((dx*svx + dy*svy + dz*svz) / fmaxf(svd2, 1e-12f), 0.0f), 1.0f);
      s.t0[0][tid] = t0v;
      float qx0 = ax + t0v*svx, qy0 = ay + t0v*svy, qz0 = az + t0v*svz;
      float ex = p0x - qx0, ey = p0y - qy0, ez = p0z - qz0;
      d2f = smf ? (ex*ex + ey*ey + ez*ez) : BIGF;
    }
    {   // backward segment tid: points (NP-1-tid, NP-2-tid)
      int i0 = 3 * (NP - 1 - tid), i1 = 3 * (NP - 2 - tid);
      float ax = s.P[i0],   ay = s.P[i0+1], az = s.P[i0+2];
      float svx = s.P[i1] - ax, svy = s.P[i1+1] - ay, svz = s.P[i1+2] - az;
      int smb = s.pmask[NP - 1 - tid] & s.pmask[NP - 2 - tid];
      float svd2 = svx*svx + svy*svy + svz*svz;
      slb = smb ? sqrtf(svd2) : 0.0f;
      s.sl[1][tid] = slb;
      float dx = p0x - ax, dy = p0y - ay, dz = p0z - az;
      float t0v = fminf(fmaxf((dx*svx + dy*svy + dz*svz) / fmaxf(svd2, 1e-12f), 0.0f), 1.0f);
      s.t0[1][tid] = t0v;
      float qx0 = ax + t0v*svx, qy0 = ay + t0v*svy, qz0 = az + t0v*svz;
      float ex = p0x - qx0, ey = p0y - qy0, ez = p0z - qz0;
      d2b = smb ? (ex*ex + ey*ey + ez*ez) : BIGF;
    }
  }
  {
    unsigned long long m = __ballot(smf != 0);
    if (lane == 0) s.wmask[w] = m;
  }
  // dual per-wave argmin (lexicographic (d2, idx) == numpy first-min, per dir order)
  for (int off = 32; off; off >>= 1) {
    float of = __shfl_xor(d2f, off, 64); int oif = __shfl_xor(idxf, off, 64);
    float ob = __shfl_xor(d2b, off, 64); int oib = __shfl_xor(idxb, off, 64);
    if (of < d2f || (of == d2f && oif < idxf)) { d2f = of; idxf = oif; }
    if (ob < d2b || (ob == d2b && oib < idxb)) { d2b = ob; idxb = oib; }
  }
  if (lane == 0) {
    s.argf[0][w] = d2f; s.argi[0][w] = idxf;
    s.argf[1][w] = d2b; s.argi[1][w] = idxb;
  }

  // traj segment length (registers)
  float tlv = 0.0f;
  if (tid < T - 1) {
    float dx = s.q[3*tid+3] - s.q[3*tid];
    float dy = s.q[3*tid+4] - s.q[3*tid+1];
    float dz = s.q[3*tid+5] - s.q[3*tid+2];
    tlv = sqrtf(dx*dx + dy*dy + dz*dz);
  }

  // --- fused triple parallel inclusive scan (sl_fw, sl_bw, traj) ---
  float xa = slf, xb = slb, xc = tlv;
  #pragma unroll
  for (int off = 1; off < 64; off <<= 1) {
    float ya = __shfl_up(xa, off, 64);
    float yb = __shfl_up(xb, off, 64);
    float yc = __shfl_up(xc, off, 64);
    if (lane >= off) { xa += ya; xb += yb; xc += yc; }
  }
  if (lane == 63) { s.wsumA[w] = xa; s.wsumB[w] = xb; s.wsumC[w] = xc; }
  __syncthreads();                              // B2: wave totals + argf/wmask/sl/t0 visible
  {
    float pa = 0.0f, pb = 0.0f, pc = 0.0f;
    if (w > 0) { pa += s.wsumA[0]; pb += s.wsumB[0]; pc += s.wsumC[0]; }
    if (w > 1) { pa += s.wsumA[1]; pb += s.wsumB[1]; pc += s.wsumC[1]; }
    if (w > 2) { pa += s.wsumA[2]; pb += s.wsumB[2]; pc += s.wsumC[2]; }
    xa += pa; xb += pb; xc += pc;
  }
  if (tid < NS)    { s.cum[0][tid + 1] = xa; s.cum[1][tid + 1] = xb; }
  if (tid < T - 1) s.tcum[tid + 1] = xc;
  if (tid == 255)  { s.cum[0][0] = 0.0f; s.cum[1][0] = 0.0f; s.tcum[0] = 0.0f; }
  __syncthreads();                              // B3: cum/tcum ready

  // --- phase B: ALL 256 threads active. waves 0-1 = fw, waves 2-3 = bw ---
  const int dir = w >> 1;                       // wave-uniform
  const int t   = tid & (T - 1);

  // block argmin + entry_s + max_valid_j for this thread's dir (broadcast LDS reads)
  float bd = s.argf[dir][0]; int bi = s.argi[dir][0];
  #pragma unroll
  for (int ww = 1; ww < 4; ++ww)
    if (s.argf[dir][ww] < bd || (s.argf[dir][ww] == bd && s.argi[dir][ww] < bi)) {
      bd = s.argf[dir][ww]; bi = s.argi[dir][ww];
    }
  float entry = s.cum[dir][bi] + s.t0[dir][bi] * s.sl[dir][bi];
  float total = dir ? (s.wsumB[0] + s.wsumB[1] + s.wsumB[2] + s.wsumB[3])
                    : (s.wsumA[0] + s.wsumA[1] + s.wsumA[2] + s.wsumA[3]);
  int anyseg = 0, mvj = 0;
  if (dir == 0) {   // highest valid fw segment
    #pragma unroll
    for (int ww = 3; ww >= 0; --ww) {
      unsigned long long m = s.wmask[ww];
      if (m) { anyseg = 1; mvj = ww * 64 + 63 - __clzll(m); break; }
    }
  } else {          // bw max_valid = NS-1 - lowest valid fw segment
    #pragma unroll
    for (int ww = 0; ww < 4; ++ww) {
      unsigned long long m = s.wmask[ww];
      if (m) { anyseg = 1; mvj = (NS - 1) - (ww * 64 + __ffsll(m) - 1); break; }
    }
  }

  // --- per-trajectory-point projection + store + distance ---
  float target = entry + s.tcum[t];
  target = fminf(target, total);
  target = fmaxf(target, 0.0f);
  int lo = 0, hi = NP;                          // j = count(cum <= target) - 1
  while (lo < hi) {
    int mid = (lo + hi) >> 1;
    if (s.cum[dir][mid] <= target) lo = mid + 1; else hi = mid;
  }
  int j = lo - 1;
  if (j < 0) j = 0;
  if (j > mvj) j = mvj;
  float tl = (target - s.cum[dir][j]) / fmaxf(s.sl[dir][j], 1e-9f);
  tl = fminf(fmaxf(tl, 0.0f), 1.0f);
  int ia, ib;
  if (dir == 0) { ia = 3 * j;            ib = ia + 3; }
  else          { ia = 3 * (NP - 1 - j); ib = 3 * (NP - 2 - j); }
  float ax = s.P[ia], ay = s.P[ia+1], az = s.P[ia+2];
  float prx = ax + tl * (s.P[ib]   - ax);
  float pry = ay + tl * (s.P[ib+1] - ay);
  float prz = az + tl * (s.P[ib+2] - az);
  {   // planar proj layout: stride-1 coalesced dword stores per plane
    size_t pb = ((size_t)(n * NB2 + dir * NB + r) * 3) * T + t;
    proj_ws[pb]         = prx;
    proj_ws[pb + T]     = pry;
    proj_ws[pb + 2 * T] = prz;
  }
  float dx = s.q[3*t] - prx, dy = s.q[3*t+1] - pry, dz = s.q[3*t+2] - prz;
  float dist = sqrtf(dx*dx + dy*dy + dz*dz);
  for (int off = 32; off; off >>= 1) dist += __shfl_xor(dist, off, 64);
  if (lane == 0) s.distf[w] = dist;
  __syncthreads();                              // B4(final): dist partials ready
  if (tid == 0) {
    cost_ws[n * NB2 + r]      = anyseg ? (s.distf[0] + s.distf[1]) : BIGF;
    cost_ws[n * NB2 + NB + r] = anyseg ? (s.distf[2] + s.distf[3]) : BIGF;
  }
}

// k2: one block per n — argmin over 32 costs, gather winning projection (planar).
__global__ __launch_bounds__(128) void k2_select(const float* __restrict__ traj,
                                                 const float* __restrict__ cost_ws,
                                                 const float* __restrict__ proj_ws,
                                                 float* __restrict__ out) {
  __shared__ int sb[2];
  const int n = (int)blockIdx.x;
  const int tid = threadIdx.x;
  if (tid < 64) {
    float cc = (tid < NB2) ? cost_ws[n * NB2 + tid] : BIGF;
    int   ii = tid;
    for (int off = 32; off; off >>= 1) {
      float oc = __shfl_xor(cc, off, 64);
      int   oi = __shfl_xor(ii, off, 64);
      if (oc < cc || (oc == cc && oi < ii)) { cc = oc; ii = oi; }  // numpy first-min
    }
    if (tid == 0) { sb[0] = ii; sb[1] = (cc < BIGF) ? 1 : 0; }
  }
  __syncthreads();
  int bi = sb[0], has = sb[1];
  int ob = (n * T + tid) * 3;
  if (has) {
    size_t pb = ((size_t)(n * NB2 + bi) * 3) * T + tid;
    out[ob + 0] = proj_ws[pb];
    out[ob + 1] = proj_ws[pb + T];
    out[ob + 2] = proj_ws[pb + 2 * T];
  } else {
    out[ob + 0] = traj[ob + 0];
    out[ob + 1] = traj[ob + 1];
    out[ob + 2] = traj[ob + 2];
  }
}

extern "C" void kernel_launch(void* const* d_in, const int* in_sizes, int n_in,
                              void* d_out, int out_size, void* d_ws, size_t ws_size,
                              hipStream_t stream) {
  const float* traj = (const float*)d_in[0];   // (N,T,3) f32 (proven bit-exact R3)
  const float* rp   = (const float*)d_in[1];   // (N,NB,NP,3) f32
  const void*  rm   = d_in[2];                 // (N,NB,NP) mask, dtype sniffed
  float* out = (float*)d_out;                  // (N,T,3) f32

  int N = in_sizes[0] / (T * 3);

  float* cost_ws = (float*)d_ws;                 // N*NB2 floats
  float* proj_ws = cost_ws + (size_t)N * NB2;    // N*NB2*3*T floats (~3 MB), planar

  k1_costs<<<dim3(N * NB), dim3(256), 0, stream>>>(traj, rp, rm, cost_ws, proj_ws);
  k2_select<<<dim3(N), dim3(128), 0, stream>>>(traj, cost_ws, proj_ws, out);
}